// Round 3
// baseline (7702.390 us; speedup 1.0000x reference)
//
#include <hip/hip_runtime.h>
#include <math.h>

#define D_DIM 512

// ---------- numpy pairwise-sum replica for sum(v*v) over 512 contiguous floats ----------
// numpy pairwise_sum: n=512 -> (P128+P128)+(P128+P128); P128 = 8-accumulator unrolled
// loop, combined ((r0+r1)+(r2+r3))+((r4+r5)+(r6+r7)). Products rounded separately
// (flat*flat is materialized f32 in numpy). __f*_rn intrinsics block FMA contraction.
__device__ __forceinline__ float pw128_sq(const float* __restrict__ a) {
    float r[8];
    #pragma unroll
    for (int j = 0; j < 8; ++j) r[j] = __fmul_rn(a[j], a[j]);
    #pragma unroll
    for (int i = 8; i < 128; i += 8)
        #pragma unroll
        for (int j = 0; j < 8; ++j) r[j] = __fadd_rn(r[j], __fmul_rn(a[i + j], a[i + j]));
    float s01 = __fadd_rn(r[0], r[1]);
    float s23 = __fadd_rn(r[2], r[3]);
    float s45 = __fadd_rn(r[4], r[5]);
    float s67 = __fadd_rn(r[6], r[7]);
    return __fadd_rn(__fadd_rn(s01, s23), __fadd_rn(s45, s67));
}
__device__ __forceinline__ float rownorm512(const float* __restrict__ row) {
    float b0 = pw128_sq(row);
    float b1 = pw128_sq(row + 128);
    float b2 = pw128_sq(row + 256);
    float b3 = pw128_sq(row + 384);
    return __fadd_rn(__fadd_rn(b0, b1), __fadd_rn(b2, b3));
}

// ---------------- K1: row squared norms (numpy-faithful f32), optional loss zero ----------------
__global__ void k_norms(const float* __restrict__ a, float* __restrict__ out,
                        int nrows, float* __restrict__ loss_ptr) {
    int r = blockIdx.x * blockDim.x + threadIdx.x;
    if (r == 0 && loss_ptr) *loss_ptr = 0.0f;
    if (r >= nrows) return;
    out[r] = rownorm512(a + (size_t)r * D_DIM);
}

// ---------------- K2: tiled distance GEMM (f64-exact dot) + f32-faithful score + argmin ----------------
constexpr int BM = 64;
constexpr int BN = 128;
constexpr int BD = 32;
constexpr int TX = 16;

struct TileView {
    float xs[BD][BM + 4];
    float es[BD][BN + 4];
};
struct RedView {
    float s[BM][TX + 1];
    int   i[BM][TX + 1];
};

__global__ __launch_bounds__(256)
void k_argmin(const float* __restrict__ x, const float* __restrict__ emb,
              const float* __restrict__ s1, const float* __restrict__ s2,
              float* __restrict__ idx_out, int N, int K) {
    __shared__ alignas(16) char smem_raw[sizeof(TileView) > sizeof(RedView)
                                         ? sizeof(TileView) : sizeof(RedView)];
    TileView& t = *reinterpret_cast<TileView*>(smem_raw);
    RedView&  r = *reinterpret_cast<RedView*>(smem_raw);
    __shared__ float ces[BN];

    const int tid = threadIdx.x;
    const int tx = tid & 15;
    const int ty = tid >> 4;
    const int rowBase = blockIdx.x * BM;
    if (rowBase >= N) return;

    float rs1[4];
    #pragma unroll
    for (int i = 0; i < 4; ++i) rs1[i] = s1[rowBase + 4 * ty + i];

    float bs[4] = {3.0e38f, 3.0e38f, 3.0e38f, 3.0e38f};
    int   bi[4] = {0, 0, 0, 0};

    for (int nt = 0; nt < K; nt += BN) {
        double acc[4][8];
        #pragma unroll
        for (int i = 0; i < 4; ++i)
            #pragma unroll
            for (int j = 0; j < 8; ++j) acc[i][j] = 0.0;

        for (int dc = 0; dc < D_DIM; dc += BD) {
            __syncthreads();
            #pragma unroll
            for (int i = 0; i < 2; ++i) {
                int q = tid + i * 256;
                int rr = q >> 3, c4 = q & 7;
                float4 v = *(const float4*)(x + (size_t)(rowBase + rr) * D_DIM + dc + 4 * c4);
                t.xs[4 * c4 + 0][rr] = v.x;
                t.xs[4 * c4 + 1][rr] = v.y;
                t.xs[4 * c4 + 2][rr] = v.z;
                t.xs[4 * c4 + 3][rr] = v.w;
            }
            #pragma unroll
            for (int i = 0; i < 4; ++i) {
                int q = tid + i * 256;
                int rr = q >> 3, c4 = q & 7;
                float4 v = *(const float4*)(emb + (size_t)(nt + rr) * D_DIM + dc + 4 * c4);
                t.es[4 * c4 + 0][rr] = v.x;
                t.es[4 * c4 + 1][rr] = v.y;
                t.es[4 * c4 + 2][rr] = v.z;
                t.es[4 * c4 + 3][rr] = v.w;
            }
            if (dc == 0 && tid < BN) ces[tid] = s2[nt + tid];
            __syncthreads();

            #pragma unroll
            for (int d = 0; d < BD; ++d) {
                float4 af = *(const float4*)&t.xs[d][4 * ty];
                float4 b0 = *(const float4*)&t.es[d][4 * tx];
                float4 b1 = *(const float4*)&t.es[d][64 + 4 * tx];
                double a[4] = {af.x, af.y, af.z, af.w};
                double b[8] = {b0.x, b0.y, b0.z, b0.w, b1.x, b1.y, b1.z, b1.w};
                #pragma unroll
                for (int i = 0; i < 4; ++i)
                    #pragma unroll
                    for (int j = 0; j < 8; ++j)
                        acc[i][j] = fma(a[i], b[j], acc[i][j]);
            }
        }
        // f32-faithful score: Q32( Q32(s1+s2) - 2*Q32(dot) ), first-occurrence argmin
        #pragma unroll
        for (int j = 0; j < 8; ++j) {
            int cc = (j < 4) ? (4 * tx + j) : (64 + 4 * tx + (j - 4));
            int code = nt + cc;
            float ce = ces[cc];
            #pragma unroll
            for (int i = 0; i < 4; ++i) {
                float tt = __fadd_rn(rs1[i], ce);
                float u  = __fmul_rn(2.0f, (float)acc[i][j]);
                float s  = __fadd_rn(tt, -u);
                if (s < bs[i]) { bs[i] = s; bi[i] = code; }
            }
        }
    }

    __syncthreads();
    #pragma unroll
    for (int i = 0; i < 4; ++i) {
        r.s[4 * ty + i][tx] = bs[i];
        r.i[4 * ty + i][tx] = bi[i];
    }
    __syncthreads();
    if (tid < BM) {
        float best = r.s[tid][0];
        int bidx = r.i[tid][0];
        #pragma unroll
        for (int tt = 1; tt < TX; ++tt) {
            float s = r.s[tid][tt];
            int ii = r.i[tid][tt];
            if (s < best || (s == best && ii < bidx)) { best = s; bidx = ii; }
        }
        idx_out[rowBase + tid] = (float)bidx;
    }
}

// ---------------- K3: gather + straight-through output + loss ----------------
__global__ __launch_bounds__(128)
void k_gather(const float* __restrict__ x, const float* __restrict__ emb,
              const float* __restrict__ idx_f, float* __restrict__ out,
              float* __restrict__ loss_ptr, float loss_scale) {
    const int row = blockIdx.x;
    const int t = threadIdx.x;
    const int idx = (int)idx_f[row];
    const float4 xv = *(const float4*)(x + (size_t)row * D_DIM + 4 * t);
    const float4 ev = *(const float4*)(emb + (size_t)idx * D_DIM + 4 * t);
    float4 o;
    o.x = xv.x * 0.95f + (ev.x - xv.x) * 0.05f;
    o.y = xv.y * 0.95f + (ev.y - xv.y) * 0.05f;
    o.z = xv.z * 0.95f + (ev.z - xv.z) * 0.05f;
    o.w = xv.w * 0.95f + (ev.w - xv.w) * 0.05f;
    *(float4*)(out + (size_t)row * D_DIM + 4 * t) = o;
    float d0 = ev.x - xv.x, d1 = ev.y - xv.y, d2 = ev.z - xv.z, d3 = ev.w - xv.w;
    float ls = d0 * d0 + d1 * d1 + d2 * d2 + d3 * d3;
    #pragma unroll
    for (int off = 32; off > 0; off >>= 1) ls += __shfl_down(ls, off, 64);
    __shared__ float wsum[2];
    if ((t & 63) == 0) wsum[t >> 6] = ls;
    __syncthreads();
    if (t == 0) atomicAdd(loss_ptr, (wsum[0] + wsum[1]) * loss_scale);
}

extern "C" void kernel_launch(void* const* d_in, const int* in_sizes, int n_in,
                              void* d_out, int out_size, void* d_ws, size_t ws_size,
                              hipStream_t stream) {
    const float* x   = (const float*)d_in[0];
    const float* emb = (const float*)d_in[1];
    const int N = in_sizes[0] / D_DIM;   // 32768
    const int K = in_sizes[1] / D_DIM;   // 8192

    float* out      = (float*)d_out;
    float* idx_out  = out + (size_t)N * D_DIM;
    float* loss_ptr = idx_out + N;
    float* s2 = (float*)d_ws;            // K floats
    float* s1 = s2 + K;                  // N floats

    // K1: numpy-faithful f32 row norms (e then x), zero loss
    k_norms<<<(K + 255) / 256, 256, 0, stream>>>(emb, s2, K, loss_ptr);
    k_norms<<<(N + 255) / 256, 256, 0, stream>>>(x, s1, N, nullptr);
    // K2: argmin over codes with f32-faithful final arithmetic
    k_argmin<<<N / BM, 256, 0, stream>>>(x, emb, s1, s2, idx_out, N, K);
    // K3: gather + output + loss
    const float loss_scale = 1.25f / ((float)N * (float)D_DIM);
    k_gather<<<N, 128, 0, stream>>>(x, emb, idx_out, out, loss_ptr, loss_scale);
}

// Round 4
// 1420.246 us; speedup vs baseline: 5.4233x; 5.4233x over previous
//
#include <hip/hip_runtime.h>
#include <math.h>

#define D_DIM 512

typedef __attribute__((ext_vector_type(8))) short bf16x8;
typedef __attribute__((ext_vector_type(4))) float f32x4;

// ---------- numpy pairwise-sum replica for sum(v*v) over 512 contiguous floats ----------
__device__ __forceinline__ float pw128_sq(const float* __restrict__ a) {
    float r[8];
    #pragma unroll
    for (int j = 0; j < 8; ++j) r[j] = __fmul_rn(a[j], a[j]);
    #pragma unroll
    for (int i = 8; i < 128; i += 8)
        #pragma unroll
        for (int j = 0; j < 8; ++j) r[j] = __fadd_rn(r[j], __fmul_rn(a[i + j], a[i + j]));
    float s01 = __fadd_rn(r[0], r[1]);
    float s23 = __fadd_rn(r[2], r[3]);
    float s45 = __fadd_rn(r[4], r[5]);
    float s67 = __fadd_rn(r[6], r[7]);
    return __fadd_rn(__fadd_rn(s01, s23), __fadd_rn(s45, s67));
}
__device__ __forceinline__ float rownorm512(const float* __restrict__ row) {
    float b0 = pw128_sq(row);
    float b1 = pw128_sq(row + 128);
    float b2 = pw128_sq(row + 256);
    float b3 = pw128_sq(row + 384);
    return __fadd_rn(__fadd_rn(b0, b1), __fadd_rn(b2, b3));
}

// ---------------- norms kernel (numpy-faithful f32) + optional zero of loss / cnt ----------------
__global__ void k_norms(const float* __restrict__ a, float* __restrict__ out, int nrows,
                        float* __restrict__ loss_ptr, unsigned* __restrict__ cnt) {
    int r = blockIdx.x * blockDim.x + threadIdx.x;
    if (r == 0 && loss_ptr) *loss_ptr = 0.0f;
    if (r >= nrows) return;
    if (cnt) cnt[r] = 0u;
    out[r] = rownorm512(a + (size_t)r * D_DIM);
}

// ---------------- f32 -> bf16 (RNE) convert, 8 elems/thread ----------------
__global__ void k_cvt_bf16(const float* __restrict__ src, unsigned short* __restrict__ dst,
                           size_t n8) {
    size_t i = blockIdx.x * (size_t)blockDim.x + threadIdx.x;
    if (i >= n8) return;
    const float4* s = (const float4*)(src + i * 8);
    float4 v0 = s[0], v1 = s[1];
    float vv[8] = {v0.x, v0.y, v0.z, v0.w, v1.x, v1.y, v1.z, v1.w};
    unsigned u[8];
    #pragma unroll
    for (int j = 0; j < 8; ++j) {
        unsigned b = __float_as_uint(vv[j]);
        b = b + 0x7FFFu + ((b >> 16) & 1u);
        u[j] = b >> 16;
    }
    uint4 w;
    w.x = u[0] | (u[1] << 16);
    w.y = u[2] | (u[3] << 16);
    w.z = u[4] | (u[5] << 16);
    w.w = u[6] | (u[7] << 16);
    *(uint4*)(dst + i * 8) = w;
}

// ---------------- MFMA filter sweep ----------------
// grid (128 Mtiles, 2 N-halves), 512 threads (8 waves as 4m x 2n, wave-tile 64x128).
// Block tile: 256 rows x 256 codes per nt step, BK=32. Running per-row min in LDS,
// candidate emission s' <= m + THETA (safe superset of all possible grid-argmin winners).
#define THETA 4.0e-4f

__global__ __launch_bounds__(512, 2)
void k_score(const unsigned short* __restrict__ Abf, const unsigned short* __restrict__ Bbf,
             const float* __restrict__ s2, unsigned* __restrict__ cnt,
             unsigned* __restrict__ cand, int N, int K) {
    __shared__ unsigned short As[256][40];   // 256 rows x 32k (+8 pad)
    __shared__ unsigned short Bs[256][40];   // 256 codes x 32k (+8 pad)
    __shared__ float s2s[256];
    __shared__ int minb[256];

    const int tid  = threadIdx.x;
    const int lane = tid & 63;
    const int wid  = tid >> 6;            // 0..7
    const int wm   = (wid >> 1) * 64;     // 0,64,128,192
    const int wn   = (wid & 1) * 128;     // 0,128
    const int col  = lane & 15;
    const int q8   = lane >> 4;           // 0..3
    const int m0   = blockIdx.x * 256;
    const int nhalf = K >> 1;             // 4096
    const int nb0  = blockIdx.y * nhalf;

    if (tid < 256) minb[tid] = 0x7F800000;  // +inf (positive-float-as-int ordering)

    for (int nt = 0; nt < nhalf; nt += 256) {
        const int nbase = nb0 + nt;
        f32x4 acc[4][8];
        #pragma unroll
        for (int mi = 0; mi < 4; ++mi)
            #pragma unroll
            for (int nj = 0; nj < 8; ++nj) acc[mi][nj] = (f32x4){0.f, 0.f, 0.f, 0.f};

        for (int kc = 0; kc < D_DIM; kc += 32) {
            __syncthreads();
            // stage A chunk: 256 rows x 32k = 1024 x 16B
            #pragma unroll
            for (int i = 0; i < 2; ++i) {
                int q = tid + i * 512;
                int r = q >> 2, c8 = q & 3;
                uint4 v = *(const uint4*)(Abf + (size_t)(m0 + r) * D_DIM + kc + c8 * 8);
                *(uint4*)&As[r][c8 * 8] = v;
            }
            // stage B chunk: 256 codes x 32k
            #pragma unroll
            for (int i = 0; i < 2; ++i) {
                int q = tid + i * 512;
                int r = q >> 2, c8 = q & 3;
                uint4 v = *(const uint4*)(Bbf + (size_t)(nbase + r) * D_DIM + kc + c8 * 8);
                *(uint4*)&Bs[r][c8 * 8] = v;
            }
            if (kc == 0 && tid < 256) s2s[tid] = s2[nbase + tid];
            __syncthreads();

            bf16x8 af[4], bfr[8];
            #pragma unroll
            for (int mi = 0; mi < 4; ++mi)
                af[mi] = *(const bf16x8*)&As[wm + mi * 16 + col][q8 * 8];
            #pragma unroll
            for (int nj = 0; nj < 8; ++nj)
                bfr[nj] = *(const bf16x8*)&Bs[wn + nj * 16 + col][q8 * 8];
            #pragma unroll
            for (int mi = 0; mi < 4; ++mi)
                #pragma unroll
                for (int nj = 0; nj < 8; ++nj)
                    acc[mi][nj] = __builtin_amdgcn_mfma_f32_16x16x32_bf16(
                        af[mi], bfr[nj], acc[mi][nj], 0, 0, 0);
        }

        // pass 1: settle per-row tile min into minb
        #pragma unroll
        for (int mi = 0; mi < 4; ++mi)
            #pragma unroll
            for (int rg = 0; rg < 4; ++rg) {
                float v = 3e38f;
                #pragma unroll
                for (int nj = 0; nj < 8; ++nj) {
                    float sc = 0.5f + fmaf(-2.0f, acc[mi][nj][rg], s2s[wn + nj * 16 + col]);
                    v = fminf(v, sc);
                }
                #pragma unroll
                for (int off = 1; off < 16; off <<= 1)
                    v = fminf(v, __shfl_xor(v, off, 64));
                if (col == 0) {
                    int rl = wm + mi * 16 + q8 * 4 + rg;
                    atomicMin(&minb[rl], __float_as_int(v));
                }
            }
        __syncthreads();

        // pass 2: emit candidates within THETA of running min
        #pragma unroll
        for (int mi = 0; mi < 4; ++mi)
            #pragma unroll
            for (int rg = 0; rg < 4; ++rg) {
                int rl = wm + mi * 16 + q8 * 4 + rg;
                float m = __int_as_float(minb[rl]);
                #pragma unroll
                for (int nj = 0; nj < 8; ++nj) {
                    float sc = 0.5f + fmaf(-2.0f, acc[mi][nj][rg], s2s[wn + nj * 16 + col]);
                    if (sc <= m + THETA) {
                        int grow = m0 + rl;
                        unsigned p = atomicAdd(&cnt[grow], 1u);
                        if (p < 32u) cand[(size_t)grow * 32 + p] = (unsigned)(nbase + wn + nj * 16 + col);
                    }
                }
            }
        __syncthreads();
    }
}

// ---------------- refine: exact f64 dot + numpy-grid f32 score over candidates ----------------
__global__ __launch_bounds__(256)
void k_refine(const float* __restrict__ x, const float* __restrict__ emb,
              const float* __restrict__ s1, const float* __restrict__ s2,
              const unsigned* __restrict__ cnt, const unsigned* __restrict__ cand,
              float* __restrict__ idx_out, int N, int K) {
    const int lane = threadIdx.x & 63;
    const int wgid = blockIdx.x * 4 + (threadIdx.x >> 6);
    const int row0 = wgid * 32;
    for (int rr = 0; rr < 32; ++rr) {
        int row = row0 + rr;
        if (row >= N) return;
        const float* xr = x + (size_t)row * D_DIM;
        float4 xa = *(const float4*)(xr + lane * 8);
        float4 xb = *(const float4*)(xr + lane * 8 + 4);
        unsigned c = cnt[row];
        float s1r = s1[row];
        float bs = 3e38f;
        int bi = 0;
        bool have = false;
        if (c >= 1u && c <= 32u) {
            for (unsigned i = 0; i < c; ++i) {
                int code = (int)cand[(size_t)row * 32 + i];
                const float* er = emb + (size_t)code * D_DIM;
                float4 ea = *(const float4*)(er + lane * 8);
                float4 eb = *(const float4*)(er + lane * 8 + 4);
                double d = 0.0;
                d = fma((double)xa.x, (double)ea.x, d);
                d = fma((double)xa.y, (double)ea.y, d);
                d = fma((double)xa.z, (double)ea.z, d);
                d = fma((double)xa.w, (double)ea.w, d);
                d = fma((double)xb.x, (double)eb.x, d);
                d = fma((double)xb.y, (double)eb.y, d);
                d = fma((double)xb.z, (double)eb.z, d);
                d = fma((double)xb.w, (double)eb.w, d);
                #pragma unroll
                for (int off = 32; off > 0; off >>= 1) d += __shfl_down(d, off, 64);
                if (lane == 0) {
                    float tt = __fadd_rn(s1r, s2[code]);
                    float u  = __fmul_rn(2.0f, (float)d);
                    float s  = __fadd_rn(tt, -u);
                    if (!have || s < bs || (s == bs && code < bi)) { bs = s; bi = code; have = true; }
                }
            }
        } else {
            // overflow (or impossible zero) -> exact full scan
            for (int code = 0; code < K; ++code) {
                const float* er = emb + (size_t)code * D_DIM;
                float4 ea = *(const float4*)(er + lane * 8);
                float4 eb = *(const float4*)(er + lane * 8 + 4);
                double d = 0.0;
                d = fma((double)xa.x, (double)ea.x, d);
                d = fma((double)xa.y, (double)ea.y, d);
                d = fma((double)xa.z, (double)ea.z, d);
                d = fma((double)xa.w, (double)ea.w, d);
                d = fma((double)xb.x, (double)eb.x, d);
                d = fma((double)xb.y, (double)eb.y, d);
                d = fma((double)xb.z, (double)eb.z, d);
                d = fma((double)xb.w, (double)eb.w, d);
                #pragma unroll
                for (int off = 32; off > 0; off >>= 1) d += __shfl_down(d, off, 64);
                if (lane == 0) {
                    float tt = __fadd_rn(s1r, s2[code]);
                    float u  = __fmul_rn(2.0f, (float)d);
                    float s  = __fadd_rn(tt, -u);
                    if (!have || s < bs) { bs = s; bi = code; have = true; }
                }
            }
        }
        if (lane == 0) idx_out[row] = (float)bi;
    }
}

// ---------------- fallback: R3's passing f64 argmin (used if ws too small) ----------------
constexpr int BM = 64;
constexpr int BN = 128;
constexpr int BD = 32;
constexpr int TX = 16;
struct TileView { float xs[BD][BM + 4]; float es[BD][BN + 4]; };
struct RedView  { float s[BM][TX + 1]; int i[BM][TX + 1]; };

__global__ __launch_bounds__(256)
void k_argmin(const float* __restrict__ x, const float* __restrict__ emb,
              const float* __restrict__ s1, const float* __restrict__ s2,
              float* __restrict__ idx_out, int N, int K) {
    __shared__ alignas(16) char smem_raw[sizeof(TileView) > sizeof(RedView)
                                         ? sizeof(TileView) : sizeof(RedView)];
    TileView& t = *reinterpret_cast<TileView*>(smem_raw);
    RedView&  r = *reinterpret_cast<RedView*>(smem_raw);
    __shared__ float ces[BN];
    const int tid = threadIdx.x;
    const int tx = tid & 15;
    const int ty = tid >> 4;
    const int rowBase = blockIdx.x * BM;
    if (rowBase >= N) return;
    float rs1[4];
    #pragma unroll
    for (int i = 0; i < 4; ++i) rs1[i] = s1[rowBase + 4 * ty + i];
    float bs[4] = {3.0e38f, 3.0e38f, 3.0e38f, 3.0e38f};
    int   bi[4] = {0, 0, 0, 0};
    for (int nt = 0; nt < K; nt += BN) {
        double acc[4][8];
        #pragma unroll
        for (int i = 0; i < 4; ++i)
            #pragma unroll
            for (int j = 0; j < 8; ++j) acc[i][j] = 0.0;
        for (int dc = 0; dc < D_DIM; dc += BD) {
            __syncthreads();
            #pragma unroll
            for (int i = 0; i < 2; ++i) {
                int q = tid + i * 256;
                int rr = q >> 3, c4 = q & 7;
                float4 v = *(const float4*)(x + (size_t)(rowBase + rr) * D_DIM + dc + 4 * c4);
                t.xs[4 * c4 + 0][rr] = v.x; t.xs[4 * c4 + 1][rr] = v.y;
                t.xs[4 * c4 + 2][rr] = v.z; t.xs[4 * c4 + 3][rr] = v.w;
            }
            #pragma unroll
            for (int i = 0; i < 4; ++i) {
                int q = tid + i * 256;
                int rr = q >> 3, c4 = q & 7;
                float4 v = *(const float4*)(emb + (size_t)(nt + rr) * D_DIM + dc + 4 * c4);
                t.es[4 * c4 + 0][rr] = v.x; t.es[4 * c4 + 1][rr] = v.y;
                t.es[4 * c4 + 2][rr] = v.z; t.es[4 * c4 + 3][rr] = v.w;
            }
            if (dc == 0 && tid < BN) ces[tid] = s2[nt + tid];
            __syncthreads();
            #pragma unroll
            for (int d = 0; d < BD; ++d) {
                float4 af = *(const float4*)&t.xs[d][4 * ty];
                float4 b0 = *(const float4*)&t.es[d][4 * tx];
                float4 b1 = *(const float4*)&t.es[d][64 + 4 * tx];
                double a[4] = {af.x, af.y, af.z, af.w};
                double b[8] = {b0.x, b0.y, b0.z, b0.w, b1.x, b1.y, b1.z, b1.w};
                #pragma unroll
                for (int i = 0; i < 4; ++i)
                    #pragma unroll
                    for (int j = 0; j < 8; ++j)
                        acc[i][j] = fma(a[i], b[j], acc[i][j]);
            }
        }
        #pragma unroll
        for (int j = 0; j < 8; ++j) {
            int cc = (j < 4) ? (4 * tx + j) : (64 + 4 * tx + (j - 4));
            int code = nt + cc;
            float ce = ces[cc];
            #pragma unroll
            for (int i = 0; i < 4; ++i) {
                float tt = __fadd_rn(rs1[i], ce);
                float u  = __fmul_rn(2.0f, (float)acc[i][j]);
                float s  = __fadd_rn(tt, -u);
                if (s < bs[i]) { bs[i] = s; bi[i] = code; }
            }
        }
    }
    __syncthreads();
    #pragma unroll
    for (int i = 0; i < 4; ++i) { r.s[4 * ty + i][tx] = bs[i]; r.i[4 * ty + i][tx] = bi[i]; }
    __syncthreads();
    if (tid < BM) {
        float best = r.s[tid][0];
        int bidx = r.i[tid][0];
        #pragma unroll
        for (int tt = 1; tt < TX; ++tt) {
            float s = r.s[tid][tt];
            int ii = r.i[tid][tt];
            if (s < best || (s == best && ii < bidx)) { best = s; bidx = ii; }
        }
        idx_out[rowBase + tid] = (float)bidx;
    }
}

// ---------------- gather + straight-through output + loss ----------------
__global__ __launch_bounds__(128)
void k_gather(const float* __restrict__ x, const float* __restrict__ emb,
              const float* __restrict__ idx_f, float* __restrict__ out,
              float* __restrict__ loss_ptr, float loss_scale) {
    const int row = blockIdx.x;
    const int t = threadIdx.x;
    const int idx = (int)idx_f[row];
    const float4 xv = *(const float4*)(x + (size_t)row * D_DIM + 4 * t);
    const float4 ev = *(const float4*)(emb + (size_t)idx * D_DIM + 4 * t);
    float4 o;
    o.x = xv.x * 0.95f + (ev.x - xv.x) * 0.05f;
    o.y = xv.y * 0.95f + (ev.y - xv.y) * 0.05f;
    o.z = xv.z * 0.95f + (ev.z - xv.z) * 0.05f;
    o.w = xv.w * 0.95f + (ev.w - xv.w) * 0.05f;
    *(float4*)(out + (size_t)row * D_DIM + 4 * t) = o;
    float d0 = ev.x - xv.x, d1 = ev.y - xv.y, d2 = ev.z - xv.z, d3 = ev.w - xv.w;
    float ls = d0 * d0 + d1 * d1 + d2 * d2 + d3 * d3;
    #pragma unroll
    for (int off = 32; off > 0; off >>= 1) ls += __shfl_down(ls, off, 64);
    __shared__ float wsum[2];
    if ((t & 63) == 0) wsum[t >> 6] = ls;
    __syncthreads();
    if (t == 0) atomicAdd(loss_ptr, (wsum[0] + wsum[1]) * loss_scale);
}

extern "C" void kernel_launch(void* const* d_in, const int* in_sizes, int n_in,
                              void* d_out, int out_size, void* d_ws, size_t ws_size,
                              hipStream_t stream) {
    const float* x   = (const float*)d_in[0];
    const float* emb = (const float*)d_in[1];
    const int N = in_sizes[0] / D_DIM;   // 32768
    const int K = in_sizes[1] / D_DIM;   // 8192

    float* out      = (float*)d_out;
    float* idx_out  = out + (size_t)N * D_DIM;
    float* loss_ptr = idx_out + N;

    char* ws = (char*)d_ws;
    size_t offA    = 0;
    size_t offB    = offA + (size_t)N * D_DIM * 2;
    size_t offS2   = offB + (size_t)K * D_DIM * 2;
    size_t offS1   = offS2 + (size_t)K * 4;
    size_t offCnt  = offS1 + (size_t)N * 4;
    size_t offCand = offCnt + (size_t)N * 4;
    size_t need    = offCand + (size_t)N * 32 * 4;

    const float loss_scale = 1.25f / ((float)N * (float)D_DIM);

    bool fast = (ws_size >= need) && (N % 256 == 0) && (K % 512 == 0);
    if (fast) {
        unsigned short* A = (unsigned short*)(ws + offA);
        unsigned short* B = (unsigned short*)(ws + offB);
        float* s2    = (float*)(ws + offS2);
        float* s1    = (float*)(ws + offS1);
        unsigned* cnt  = (unsigned*)(ws + offCnt);
        unsigned* cand = (unsigned*)(ws + offCand);

        k_norms<<<(K + 255) / 256, 256, 0, stream>>>(emb, s2, K, loss_ptr, nullptr);
        k_norms<<<(N + 255) / 256, 256, 0, stream>>>(x, s1, N, nullptr, cnt);
        k_cvt_bf16<<<(N * (D_DIM / 8)) / 256, 256, 0, stream>>>(x, A, (size_t)N * (D_DIM / 8));
        k_cvt_bf16<<<(K * (D_DIM / 8)) / 256, 256, 0, stream>>>(emb, B, (size_t)K * (D_DIM / 8));
        k_score<<<dim3(N / 256, 2), 512, 0, stream>>>(A, B, s2, cnt, cand, N, K);
        k_refine<<<N / 128, 256, 0, stream>>>(x, emb, s1, s2, cnt, cand, idx_out, N, K);
    } else {
        float* s2 = (float*)d_ws;
        float* s1 = s2 + K;
        k_norms<<<(K + 255) / 256, 256, 0, stream>>>(emb, s2, K, loss_ptr, nullptr);
        k_norms<<<(N + 255) / 256, 256, 0, stream>>>(x, s1, N, nullptr, nullptr);
        k_argmin<<<N / BM, 256, 0, stream>>>(x, emb, s1, s2, idx_out, N, K);
    }
    k_gather<<<N, 128, 0, stream>>>(x, emb, idx_out, out, loss_ptr, loss_scale);
}